// Round 10
// baseline (145.536 us; speedup 1.0000x reference)
//
#include <hip/hip_runtime.h>
#include <stdint.h>

// DiffLogic: 3-layer differentiable logic network.
// Round 16: R15 (global-gather + SMEM metadata) is latency-dominated:
// ~150 instr/gate-eval * 64K evals = ~8us of VALU issue vs ~35us measured.
// Chain per iter: 9 s_loads (meta, mostly cross-XCD L2 miss ~300-900cy) ->
// lgkmcnt -> 8 gathers (~250cy) -> vmcnt -> compute; unroll 2 = only 2
// chains in flight, 4 waves/SIMD is the occupancy ceiling (8 needs VGPR<=64
// = proven spill). Single change: unroll 4 -> 4 meta records + 32 gathers
// in flight per wave (~100-120 VGPR live, under the 128 cap). Meta pointer
// forced uniform via readfirstlane (guaranteed s_load, can't regress).

#define BATCH   256
#define IN_DIM  1024
#define WIDTH   64000
#define NGROUP  10
#define GSIZE   6400      // WIDTH / NGROUP
#define TAU     30.0f
#define NWAVE   16        // waves per block (1024 threads)
#define GPB3    256       // gates per block; 6400 % 256 == 0 -> no straddle
#define GPW3    (GPB3/NWAVE)   // 16 gates per wave
#define NBLK3   (WIDTH/GPB3)   // 250 blocks -> single pass on 256 CUs
#define BPG     (GSIZE/GPB3)   // 25 blocks per output group

typedef unsigned short ushort_t;

static __device__ __forceinline__ ushort_t f2bf(float f) {   // RNE
    uint32_t u = __float_as_uint(f);
    return (ushort_t)((u + 0x7fffu + ((u >> 16) & 1u)) >> 16);
}
static __device__ __forceinline__ float bfl(uint32_t u) {    // low bf16 -> f32
    return __uint_as_float(u << 16);
}
static __device__ __forceinline__ float bfh(uint32_t u) {    // high bf16 -> f32
    return __uint_as_float(u & 0xffff0000u);
}
// h = c0 + c1*a + c2*b + c3*(a*b) = b*(c3*a+c2) + (c1*a+c0)  -- 3 FMA
static __device__ __forceinline__ float gate1(float4 c, float a, float b) {
    return fmaf(b, fmaf(c.w, a, c.z), fmaf(c.y, a, c.x));
}
static __device__ __forceinline__ float4 gate4(float4 c, float4 a, float4 b) {
    float4 r;
    r.x = gate1(c, a.x, b.x);
    r.y = gate1(c, a.y, b.y);
    r.z = gate1(c, a.z, b.z);
    r.w = gate1(c, a.w, b.w);
    return r;
}
// packed inputs: a,b are uint2 holding 4 bf16 batch elems each
static __device__ __forceinline__ float4 gate4u(float4 c, uint2 a, uint2 b) {
    float4 r;
    r.x = gate1(c, bfl(a.x), bfl(b.x));
    r.y = gate1(c, bfh(a.x), bfh(b.x));
    r.z = gate1(c, bfl(a.y), bfl(b.y));
    r.w = gate1(c, bfh(a.y), bfh(b.y));
    return r;
}
// force a (known-uniform) pointer into SGPRs so loads through it scalarize
static __device__ __forceinline__ const int* uniform_ptr(const int* p) {
    unsigned long long u = (unsigned long long)p;
    unsigned int lo = __builtin_amdgcn_readfirstlane((unsigned int)u);
    unsigned int hi = __builtin_amdgcn_readfirstlane((unsigned int)(u >> 32));
    return (const int*)(((unsigned long long)hi << 32) | lo);
}

// ---------------------------------------------------------------- transpose
// x:(256,1024) f32 row-major -> xT:(1024,256) bf16
__global__ __launch_bounds__(256) void transpose_kernel(
    const float* __restrict__ x, ushort_t* __restrict__ xT)
{
    __shared__ float tile[64][65];
    const int c0 = (blockIdx.x & 15) * 64;
    const int b0 = (blockIdx.x >> 4) * 64;
    const int lt = threadIdx.x & 63;
    const int wt = threadIdx.x >> 6;
    for (int r = wt; r < 64; r += 4)
        tile[r][lt] = x[(b0 + r) * IN_DIM + c0 + lt];
    __syncthreads();
    for (int r = wt; r < 64; r += 4)
        xT[(c0 + r) * BATCH + b0 + lt] = f2bf(tile[lt][r]);
}

// ---------------------------------------------------------------- coefficients
__global__ __launch_bounds__(256) void coef_kernel(
    const float* __restrict__ w1, const float* __restrict__ w2,
    const float* __restrict__ w3,
    float4* __restrict__ c1o, float4* __restrict__ c2o, float4* __restrict__ c3o)
{
    const int id = blockIdx.x * 256 + threadIdx.x;
    const int layer = id / WIDTH;
    const int j = id - layer * WIDTH;
    const float* w = (layer == 0) ? w1 : (layer == 1) ? w2 : w3;
    float4* cc     = (layer == 0) ? c1o : (layer == 1) ? c2o : c3o;

    const float4* w4 = (const float4*)(w + (size_t)j * 16);
    float4 q0 = w4[0], q1 = w4[1], q2 = w4[2], q3 = w4[3];
    float p[16] = {q0.x,q0.y,q0.z,q0.w, q1.x,q1.y,q1.z,q1.w,
                   q2.x,q2.y,q2.z,q2.w, q3.x,q3.y,q3.z,q3.w};
    float m = p[0];
    #pragma unroll
    for (int i = 1; i < 16; ++i) m = fmaxf(m, p[i]);
    float s = 0.f;
    #pragma unroll
    for (int i = 0; i < 16; ++i) { p[i] = __expf(p[i] - m); s += p[i]; }
    const float inv = 1.0f / s;
    float c0 = (p[8]+p[9]+p[10]+p[11]+p[12]+p[13]+p[14]+p[15]) * inv;
    float c1 = (p[2]+p[3]+p[6]+p[7] - p[8]-p[9]-p[12]-p[13]) * inv;
    float c2 = (p[4]+p[5]+p[6]+p[7] - p[8]-p[9]-p[10]-p[11]) * inv;
    float c3 = (p[1]-p[2]-p[4]-2.f*p[6]-p[7]+p[8]+2.f*p[9]+p[11]+p[13]-p[14]) * inv;
    cc[j] = make_float4(c0, c1, c2, c3);
}

// ---------------------------------------------------------------- tree prep
// One thread per final gate j: flatten its depth-3 tree into a single
// 36-dword record: [iA(4) | iB(4) | K0..K6(28)] -> s_loads in the hot loop.
__global__ __launch_bounds__(256) void prep_kernel(
    const int* __restrict__ ia1, const int* __restrict__ ib1,
    const int* __restrict__ ia2, const int* __restrict__ ib2,
    const int* __restrict__ ia3, const int* __restrict__ ib3,
    const float4* __restrict__ c1, const float4* __restrict__ c2,
    const float4* __restrict__ c3,
    int* __restrict__ meta)        // [WIDTH][36]
{
    const int j = blockIdx.x * 256 + threadIdx.x;
    if (j >= WIDTH) return;

    const int pa = ia3[j], pb = ib3[j];
    const int qaa = ia2[pa], qab = ib2[pa];
    const int qba = ia2[pb], qbb = ib2[pb];

    int* M = meta + (size_t)j * 36;
    M[0] = ia1[qaa]; M[1] = ib1[qaa];
    M[2] = ia1[qab]; M[3] = ib1[qab];
    M[4] = ia1[qba]; M[5] = ib1[qba];
    M[6] = ia1[qbb]; M[7] = ib1[qbb];

    float4* P = (float4*)(M + 8);
    P[0] = c1[qaa]; P[1] = c1[qab]; P[2] = c1[qba]; P[3] = c1[qbb];
    P[4] = c2[pa];  P[5] = c2[pb];
    P[6] = c3[j];
}

// ---------------------------------------------------------------- fused net
__global__ __launch_bounds__(1024, 4) void fused_kernel(
    const ushort_t* __restrict__ xT,
    const int*      __restrict__ meta,
    float*          __restrict__ red_out)
{
    __shared__ float4 sred[NWAVE][64];       // 16 KB

    const int tid  = threadIdx.x;
    const int lane = tid & 63;
    const int wu   = __builtin_amdgcn_readfirstlane(tid >> 6);
    const int g0   = blockIdx.x * GPB3 + wu * GPW3;   // uniform

    // wave's metadata stream: contiguous 16 x 36 dwords, SGPR-resident base
    const int* mp = uniform_ptr(meta + (size_t)g0 * 36);

    float4 acc = make_float4(0.f, 0.f, 0.f, 0.f);

    #pragma unroll 4
    for (int i = 0; i < GPW3; ++i) {
        const int4 iA   = *(const int4*)(mp);             // s_load
        const int4 iB   = *(const int4*)(mp + 4);
        const float4 K0 = *(const float4*)(mp + 8);
        const float4 K1 = *(const float4*)(mp + 12);
        const float4 K2 = *(const float4*)(mp + 16);
        const float4 K3 = *(const float4*)(mp + 20);
        const float4 K4 = *(const float4*)(mp + 24);
        const float4 K5 = *(const float4*)(mp + 28);
        const float4 K6 = *(const float4*)(mp + 32);
        mp += 36;

        // 8 saddr-form gathers: SGPR col base + lane*8 voffset, L2-resident
        const uint2 q0 = ((const uint2*)(xT + (size_t)iA.x * BATCH))[lane];
        const uint2 q1 = ((const uint2*)(xT + (size_t)iA.y * BATCH))[lane];
        const uint2 q2 = ((const uint2*)(xT + (size_t)iA.z * BATCH))[lane];
        const uint2 q3 = ((const uint2*)(xT + (size_t)iA.w * BATCH))[lane];
        const uint2 q4 = ((const uint2*)(xT + (size_t)iB.x * BATCH))[lane];
        const uint2 q5 = ((const uint2*)(xT + (size_t)iB.y * BATCH))[lane];
        const uint2 q6 = ((const uint2*)(xT + (size_t)iB.z * BATCH))[lane];
        const uint2 q7 = ((const uint2*)(xT + (size_t)iB.w * BATCH))[lane];

        const float4 haa = gate4u(K0, q0, q1);
        const float4 hab = gate4u(K1, q2, q3);
        const float4 hba = gate4u(K2, q4, q5);
        const float4 hbb = gate4u(K3, q6, q7);
        const float4 h2a = gate4(K4, haa, hab);
        const float4 h2b = gate4(K5, hba, hbb);
        const float4 h3  = gate4(K6, h2a, h2b);
        acc.x += h3.x; acc.y += h3.y; acc.z += h3.z; acc.w += h3.w;
    }

    // ---- block reduction + grouped atomic add (block fully inside a group)
    sred[wu][lane] = acc;
    __syncthreads();
    if (wu == 0) {
        float4 t = sred[0][lane];
        #pragma unroll
        for (int w = 1; w < NWAVE; ++w) {
            float4 q = sred[w][lane];
            t.x += q.x; t.y += q.y; t.z += q.z; t.w += q.w;
        }
        const float sc = 1.0f / TAU;
        const int grp = blockIdx.x / BPG;
        const int b0 = lane * 4;
        atomicAdd(&red_out[(b0 + 0) * NGROUP + grp], t.x * sc);
        atomicAdd(&red_out[(b0 + 1) * NGROUP + grp], t.y * sc);
        atomicAdd(&red_out[(b0 + 2) * NGROUP + grp], t.z * sc);
        atomicAdd(&red_out[(b0 + 3) * NGROUP + grp], t.w * sc);
    }
}

// ---------------------------------------------------------------- launch
extern "C" void kernel_launch(void* const* d_in, const int* in_sizes, int n_in,
                              void* d_out, int out_size, void* d_ws, size_t ws_size,
                              hipStream_t stream)
{
    const float* x   = (const float*)d_in[0];
    const float* w1  = (const float*)d_in[1];
    const float* w2  = (const float*)d_in[2];
    const float* w3  = (const float*)d_in[3];
    const int*   ia1 = (const int*)d_in[4];
    const int*   ib1 = (const int*)d_in[5];
    const int*   ia2 = (const int*)d_in[6];
    const int*   ib2 = (const int*)d_in[7];
    const int*   ia3 = (const int*)d_in[8];
    const int*   ib3 = (const int*)d_in[9];
    float* out = (float*)d_out;

    // workspace: xT (0.5MB) | meta (9.2MB) | c1,c2,c3 (3MB) ~= 12.7MB
    char* ws = (char*)d_ws;
    ushort_t* xT = (ushort_t*)ws;
    int*    meta = (int*)(ws + (size_t)IN_DIM * BATCH * 2);
    float4*   c1 = (float4*)(meta + (size_t)WIDTH * 36);
    float4*   c2 = c1 + WIDTH;
    float4*   c3 = c2 + WIDTH;

    hipMemsetAsync(d_out, 0, (size_t)out_size * sizeof(float), stream);

    transpose_kernel<<<64, 256, 0, stream>>>(x, xT);
    coef_kernel<<<(3 * WIDTH) / 256, 256, 0, stream>>>(w1, w2, w3, c1, c2, c3);
    prep_kernel<<<WIDTH / 256, 256, 0, stream>>>(ia1, ib1, ia2, ib2, ia3, ib3,
                                                 c1, c2, c3, meta);
    fused_kernel<<<NBLK3, 1024, 0, stream>>>(xT, meta, out);
}

// Round 11
// 141.876 us; speedup vs baseline: 1.0258x; 1.0258x over previous
//
#include <hip/hip_runtime.h>
#include <stdint.h>

// DiffLogic: 3-layer differentiable logic network.
// Round 17: two counter findings from R16. (1) SGPR 112->32: the
// uniform_ptr readfirstlane-reassembly DEFEATED the scalarizer -- meta
// loads fell off the scalar pipe. Restore R14's direct uniform-index
// access meta[(uniform g)*36] (proven s_load, SGPR=112). (2) VGPR=40,
// VALUBusy=23%, 1 block/CU: the kernel is latency-bound at 4 waves/SIMD
// while its live set already fits 8. Halve the block (128 gates) ->
// 500 blocks x 1024 thr = 2 blocks/CU = 8 waves/SIMD via
// __launch_bounds__(1024,8) (cap 64; measured live set 40). Unroll 2:
// let TLP hide latency instead of fragile ILP. 6400%128==0 -> no straddle.

#define BATCH   256
#define IN_DIM  1024
#define WIDTH   64000
#define NGROUP  10
#define GSIZE   6400      // WIDTH / NGROUP
#define TAU     30.0f
#define NWAVE   16        // waves per block (1024 threads)
#define GPB3    128       // gates per block; 6400 % 128 == 0 -> no straddle
#define GPW3    (GPB3/NWAVE)   // 8 gates per wave
#define NBLK3   (WIDTH/GPB3)   // 500 blocks -> 2 blocks/CU, 8 waves/SIMD
#define BPG     (GSIZE/GPB3)   // 50 blocks per output group

typedef unsigned short ushort_t;

static __device__ __forceinline__ ushort_t f2bf(float f) {   // RNE
    uint32_t u = __float_as_uint(f);
    return (ushort_t)((u + 0x7fffu + ((u >> 16) & 1u)) >> 16);
}
static __device__ __forceinline__ float bfl(uint32_t u) {    // low bf16 -> f32
    return __uint_as_float(u << 16);
}
static __device__ __forceinline__ float bfh(uint32_t u) {    // high bf16 -> f32
    return __uint_as_float(u & 0xffff0000u);
}
// h = c0 + c1*a + c2*b + c3*(a*b) = b*(c3*a+c2) + (c1*a+c0)  -- 3 FMA
static __device__ __forceinline__ float gate1(float4 c, float a, float b) {
    return fmaf(b, fmaf(c.w, a, c.z), fmaf(c.y, a, c.x));
}
static __device__ __forceinline__ float4 gate4(float4 c, float4 a, float4 b) {
    float4 r;
    r.x = gate1(c, a.x, b.x);
    r.y = gate1(c, a.y, b.y);
    r.z = gate1(c, a.z, b.z);
    r.w = gate1(c, a.w, b.w);
    return r;
}
// packed inputs: a,b are uint2 holding 4 bf16 batch elems each
static __device__ __forceinline__ float4 gate4u(float4 c, uint2 a, uint2 b) {
    float4 r;
    r.x = gate1(c, bfl(a.x), bfl(b.x));
    r.y = gate1(c, bfh(a.x), bfh(b.x));
    r.z = gate1(c, bfl(a.y), bfl(b.y));
    r.w = gate1(c, bfh(a.y), bfh(b.y));
    return r;
}

// ---------------------------------------------------------------- transpose
// x:(256,1024) f32 row-major -> xT:(1024,256) bf16
__global__ __launch_bounds__(256) void transpose_kernel(
    const float* __restrict__ x, ushort_t* __restrict__ xT)
{
    __shared__ float tile[64][65];
    const int c0 = (blockIdx.x & 15) * 64;
    const int b0 = (blockIdx.x >> 4) * 64;
    const int lt = threadIdx.x & 63;
    const int wt = threadIdx.x >> 6;
    for (int r = wt; r < 64; r += 4)
        tile[r][lt] = x[(b0 + r) * IN_DIM + c0 + lt];
    __syncthreads();
    for (int r = wt; r < 64; r += 4)
        xT[(c0 + r) * BATCH + b0 + lt] = f2bf(tile[lt][r]);
}

// ---------------------------------------------------------------- coefficients
__global__ __launch_bounds__(256) void coef_kernel(
    const float* __restrict__ w1, const float* __restrict__ w2,
    const float* __restrict__ w3,
    float4* __restrict__ c1o, float4* __restrict__ c2o, float4* __restrict__ c3o)
{
    const int id = blockIdx.x * 256 + threadIdx.x;
    const int layer = id / WIDTH;
    const int j = id - layer * WIDTH;
    const float* w = (layer == 0) ? w1 : (layer == 1) ? w2 : w3;
    float4* cc     = (layer == 0) ? c1o : (layer == 1) ? c2o : c3o;

    const float4* w4 = (const float4*)(w + (size_t)j * 16);
    float4 q0 = w4[0], q1 = w4[1], q2 = w4[2], q3 = w4[3];
    float p[16] = {q0.x,q0.y,q0.z,q0.w, q1.x,q1.y,q1.z,q1.w,
                   q2.x,q2.y,q2.z,q2.w, q3.x,q3.y,q3.z,q3.w};
    float m = p[0];
    #pragma unroll
    for (int i = 1; i < 16; ++i) m = fmaxf(m, p[i]);
    float s = 0.f;
    #pragma unroll
    for (int i = 0; i < 16; ++i) { p[i] = __expf(p[i] - m); s += p[i]; }
    const float inv = 1.0f / s;
    float c0 = (p[8]+p[9]+p[10]+p[11]+p[12]+p[13]+p[14]+p[15]) * inv;
    float c1 = (p[2]+p[3]+p[6]+p[7] - p[8]-p[9]-p[12]-p[13]) * inv;
    float c2 = (p[4]+p[5]+p[6]+p[7] - p[8]-p[9]-p[10]-p[11]) * inv;
    float c3 = (p[1]-p[2]-p[4]-2.f*p[6]-p[7]+p[8]+2.f*p[9]+p[11]+p[13]-p[14]) * inv;
    cc[j] = make_float4(c0, c1, c2, c3);
}

// ---------------------------------------------------------------- tree prep
// One thread per final gate j: flatten its depth-3 tree into a single
// 36-dword record: [iA(4) | iB(4) | K0..K6(28)] -> s_loads in the hot loop.
__global__ __launch_bounds__(256) void prep_kernel(
    const int* __restrict__ ia1, const int* __restrict__ ib1,
    const int* __restrict__ ia2, const int* __restrict__ ib2,
    const int* __restrict__ ia3, const int* __restrict__ ib3,
    const float4* __restrict__ c1, const float4* __restrict__ c2,
    const float4* __restrict__ c3,
    int* __restrict__ meta)        // [WIDTH][36]
{
    const int j = blockIdx.x * 256 + threadIdx.x;
    if (j >= WIDTH) return;

    const int pa = ia3[j], pb = ib3[j];
    const int qaa = ia2[pa], qab = ib2[pa];
    const int qba = ia2[pb], qbb = ib2[pb];

    int* M = meta + (size_t)j * 36;
    M[0] = ia1[qaa]; M[1] = ib1[qaa];
    M[2] = ia1[qab]; M[3] = ib1[qab];
    M[4] = ia1[qba]; M[5] = ib1[qba];
    M[6] = ia1[qbb]; M[7] = ib1[qbb];

    float4* P = (float4*)(M + 8);
    P[0] = c1[qaa]; P[1] = c1[qab]; P[2] = c1[qba]; P[3] = c1[qbb];
    P[4] = c2[pa];  P[5] = c2[pb];
    P[6] = c3[j];
}

// ---------------------------------------------------------------- fused net
__global__ __launch_bounds__(1024, 8) void fused_kernel(
    const ushort_t* __restrict__ xT,
    const int*      __restrict__ meta,
    float*          __restrict__ red_out)
{
    __shared__ float4 sred[NWAVE][64];       // 16 KB

    const int tid  = threadIdx.x;
    const int lane = tid & 63;
    const int wu   = __builtin_amdgcn_readfirstlane(tid >> 6);
    const int g0   = blockIdx.x * GPB3 + wu * GPW3;   // uniform (proven R14)

    float4 acc = make_float4(0.f, 0.f, 0.f, 0.f);

    #pragma unroll 2
    for (int i = 0; i < GPW3; ++i) {
        const int g = g0 + i;                         // uniform int index
        const int* mp = meta + (size_t)g * 36;        // -> s_load (R14 form)
        const int4 iA   = *(const int4*)(mp);
        const int4 iB   = *(const int4*)(mp + 4);
        const float4 K0 = *(const float4*)(mp + 8);
        const float4 K1 = *(const float4*)(mp + 12);
        const float4 K2 = *(const float4*)(mp + 16);
        const float4 K3 = *(const float4*)(mp + 20);
        const float4 K4 = *(const float4*)(mp + 24);
        const float4 K5 = *(const float4*)(mp + 28);
        const float4 K6 = *(const float4*)(mp + 32);

        // 8 saddr-form gathers: SGPR col base + lane*8 voffset, L2-resident
        const uint2 q0 = ((const uint2*)(xT + (size_t)iA.x * BATCH))[lane];
        const uint2 q1 = ((const uint2*)(xT + (size_t)iA.y * BATCH))[lane];
        const uint2 q2 = ((const uint2*)(xT + (size_t)iA.z * BATCH))[lane];
        const uint2 q3 = ((const uint2*)(xT + (size_t)iA.w * BATCH))[lane];
        const uint2 q4 = ((const uint2*)(xT + (size_t)iB.x * BATCH))[lane];
        const uint2 q5 = ((const uint2*)(xT + (size_t)iB.y * BATCH))[lane];
        const uint2 q6 = ((const uint2*)(xT + (size_t)iB.z * BATCH))[lane];
        const uint2 q7 = ((const uint2*)(xT + (size_t)iB.w * BATCH))[lane];

        const float4 haa = gate4u(K0, q0, q1);
        const float4 hab = gate4u(K1, q2, q3);
        const float4 hba = gate4u(K2, q4, q5);
        const float4 hbb = gate4u(K3, q6, q7);
        const float4 h2a = gate4(K4, haa, hab);
        const float4 h2b = gate4(K5, hba, hbb);
        const float4 h3  = gate4(K6, h2a, h2b);
        acc.x += h3.x; acc.y += h3.y; acc.z += h3.z; acc.w += h3.w;
    }

    // ---- block reduction + grouped atomic add (block fully inside a group)
    sred[wu][lane] = acc;
    __syncthreads();
    if (wu == 0) {
        float4 t = sred[0][lane];
        #pragma unroll
        for (int w = 1; w < NWAVE; ++w) {
            float4 q = sred[w][lane];
            t.x += q.x; t.y += q.y; t.z += q.z; t.w += q.w;
        }
        const float sc = 1.0f / TAU;
        const int grp = blockIdx.x / BPG;
        const int b0 = lane * 4;
        atomicAdd(&red_out[(b0 + 0) * NGROUP + grp], t.x * sc);
        atomicAdd(&red_out[(b0 + 1) * NGROUP + grp], t.y * sc);
        atomicAdd(&red_out[(b0 + 2) * NGROUP + grp], t.z * sc);
        atomicAdd(&red_out[(b0 + 3) * NGROUP + grp], t.w * sc);
    }
}

// ---------------------------------------------------------------- launch
extern "C" void kernel_launch(void* const* d_in, const int* in_sizes, int n_in,
                              void* d_out, int out_size, void* d_ws, size_t ws_size,
                              hipStream_t stream)
{
    const float* x   = (const float*)d_in[0];
    const float* w1  = (const float*)d_in[1];
    const float* w2  = (const float*)d_in[2];
    const float* w3  = (const float*)d_in[3];
    const int*   ia1 = (const int*)d_in[4];
    const int*   ib1 = (const int*)d_in[5];
    const int*   ia2 = (const int*)d_in[6];
    const int*   ib2 = (const int*)d_in[7];
    const int*   ia3 = (const int*)d_in[8];
    const int*   ib3 = (const int*)d_in[9];
    float* out = (float*)d_out;

    // workspace: xT (0.5MB) | meta (9.2MB) | c1,c2,c3 (3MB) ~= 12.7MB
    char* ws = (char*)d_ws;
    ushort_t* xT = (ushort_t*)ws;
    int*    meta = (int*)(ws + (size_t)IN_DIM * BATCH * 2);
    float4*   c1 = (float4*)(meta + (size_t)WIDTH * 36);
    float4*   c2 = c1 + WIDTH;
    float4*   c3 = c2 + WIDTH;

    hipMemsetAsync(d_out, 0, (size_t)out_size * sizeof(float), stream);

    transpose_kernel<<<64, 256, 0, stream>>>(x, xT);
    coef_kernel<<<(3 * WIDTH) / 256, 256, 0, stream>>>(w1, w2, w3, c1, c2, c3);
    prep_kernel<<<WIDTH / 256, 256, 0, stream>>>(ia1, ib1, ia2, ib2, ia3, ib3,
                                                 c1, c2, c3, meta);
    fused_kernel<<<NBLK3, 1024, 0, stream>>>(xT, meta, out);
}

// Round 12
// 137.468 us; speedup vs baseline: 1.0587x; 1.0321x over previous
//
#include <hip/hip_runtime.h>
#include <stdint.h>

// DiffLogic: 3-layer differentiable logic network.
// Round 18: R17's regression decoded: __launch_bounds__(1024,8) forced a
// 64-VGPR cap -> allocator overshot to 32 and SPILLED (WRITE 23MB); the
// occupancy gain (31->49%) was eaten by per-wave slowdown. Lesson: the
// bounds arg caps REGISTERS; occupancy comes from the GRID. This round:
// exact R15 kernel (proven best, fused ~35us at 250 blocks = 1 block/CU),
// ONE change -- GPB 256->128 => 500 blocks = 2 blocks/CU = up to 8
// waves/SIMD, with (1024,4) so the allocator keeps its no-spill budget.
// 6400 % 128 == 0 -> still no group straddle. All else byte-identical.

#define BATCH   256
#define IN_DIM  1024
#define WIDTH   64000
#define NGROUP  10
#define GSIZE   6400      // WIDTH / NGROUP
#define TAU     30.0f
#define NWAVE   16        // waves per block (1024 threads)
#define GPB3    128       // gates per block; 6400 % 128 == 0 -> no straddle
#define GPW3    (GPB3/NWAVE)   // 8 gates per wave
#define NBLK3   (WIDTH/GPB3)   // 500 blocks -> 2 blocks/CU
#define BPG     (GSIZE/GPB3)   // 50 blocks per output group

typedef unsigned short ushort_t;

static __device__ __forceinline__ ushort_t f2bf(float f) {   // RNE
    uint32_t u = __float_as_uint(f);
    return (ushort_t)((u + 0x7fffu + ((u >> 16) & 1u)) >> 16);
}
static __device__ __forceinline__ float bfl(uint32_t u) {    // low bf16 -> f32
    return __uint_as_float(u << 16);
}
static __device__ __forceinline__ float bfh(uint32_t u) {    // high bf16 -> f32
    return __uint_as_float(u & 0xffff0000u);
}
// h = c0 + c1*a + c2*b + c3*(a*b) = b*(c3*a+c2) + (c1*a+c0)  -- 3 FMA
static __device__ __forceinline__ float gate1(float4 c, float a, float b) {
    return fmaf(b, fmaf(c.w, a, c.z), fmaf(c.y, a, c.x));
}
static __device__ __forceinline__ float4 gate4(float4 c, float4 a, float4 b) {
    float4 r;
    r.x = gate1(c, a.x, b.x);
    r.y = gate1(c, a.y, b.y);
    r.z = gate1(c, a.z, b.z);
    r.w = gate1(c, a.w, b.w);
    return r;
}
// packed inputs: a,b are uint2 holding 4 bf16 batch elems each
static __device__ __forceinline__ float4 gate4u(float4 c, uint2 a, uint2 b) {
    float4 r;
    r.x = gate1(c, bfl(a.x), bfl(b.x));
    r.y = gate1(c, bfh(a.x), bfh(b.x));
    r.z = gate1(c, bfl(a.y), bfl(b.y));
    r.w = gate1(c, bfh(a.y), bfh(b.y));
    return r;
}

// ---------------------------------------------------------------- transpose
// x:(256,1024) f32 row-major -> xT:(1024,256) bf16
__global__ __launch_bounds__(256) void transpose_kernel(
    const float* __restrict__ x, ushort_t* __restrict__ xT)
{
    __shared__ float tile[64][65];
    const int c0 = (blockIdx.x & 15) * 64;
    const int b0 = (blockIdx.x >> 4) * 64;
    const int lt = threadIdx.x & 63;
    const int wt = threadIdx.x >> 6;
    for (int r = wt; r < 64; r += 4)
        tile[r][lt] = x[(b0 + r) * IN_DIM + c0 + lt];
    __syncthreads();
    for (int r = wt; r < 64; r += 4)
        xT[(c0 + r) * BATCH + b0 + lt] = f2bf(tile[lt][r]);
}

// ---------------------------------------------------------------- coefficients
__global__ __launch_bounds__(256) void coef_kernel(
    const float* __restrict__ w1, const float* __restrict__ w2,
    const float* __restrict__ w3,
    float4* __restrict__ c1o, float4* __restrict__ c2o, float4* __restrict__ c3o)
{
    const int id = blockIdx.x * 256 + threadIdx.x;
    const int layer = id / WIDTH;
    const int j = id - layer * WIDTH;
    const float* w = (layer == 0) ? w1 : (layer == 1) ? w2 : w3;
    float4* cc     = (layer == 0) ? c1o : (layer == 1) ? c2o : c3o;

    const float4* w4 = (const float4*)(w + (size_t)j * 16);
    float4 q0 = w4[0], q1 = w4[1], q2 = w4[2], q3 = w4[3];
    float p[16] = {q0.x,q0.y,q0.z,q0.w, q1.x,q1.y,q1.z,q1.w,
                   q2.x,q2.y,q2.z,q2.w, q3.x,q3.y,q3.z,q3.w};
    float m = p[0];
    #pragma unroll
    for (int i = 1; i < 16; ++i) m = fmaxf(m, p[i]);
    float s = 0.f;
    #pragma unroll
    for (int i = 0; i < 16; ++i) { p[i] = __expf(p[i] - m); s += p[i]; }
    const float inv = 1.0f / s;
    float c0 = (p[8]+p[9]+p[10]+p[11]+p[12]+p[13]+p[14]+p[15]) * inv;
    float c1 = (p[2]+p[3]+p[6]+p[7] - p[8]-p[9]-p[12]-p[13]) * inv;
    float c2 = (p[4]+p[5]+p[6]+p[7] - p[8]-p[9]-p[10]-p[11]) * inv;
    float c3 = (p[1]-p[2]-p[4]-2.f*p[6]-p[7]+p[8]+2.f*p[9]+p[11]+p[13]-p[14]) * inv;
    cc[j] = make_float4(c0, c1, c2, c3);
}

// ---------------------------------------------------------------- tree prep
// One thread per final gate j: flatten its depth-3 tree into a single
// 36-dword record: [iA(4) | iB(4) | K0..K6(28)] -> s_loads in the hot loop.
__global__ __launch_bounds__(256) void prep_kernel(
    const int* __restrict__ ia1, const int* __restrict__ ib1,
    const int* __restrict__ ia2, const int* __restrict__ ib2,
    const int* __restrict__ ia3, const int* __restrict__ ib3,
    const float4* __restrict__ c1, const float4* __restrict__ c2,
    const float4* __restrict__ c3,
    int* __restrict__ meta)        // [WIDTH][36]
{
    const int j = blockIdx.x * 256 + threadIdx.x;
    if (j >= WIDTH) return;

    const int pa = ia3[j], pb = ib3[j];
    const int qaa = ia2[pa], qab = ib2[pa];
    const int qba = ia2[pb], qbb = ib2[pb];

    int* M = meta + (size_t)j * 36;
    M[0] = ia1[qaa]; M[1] = ib1[qaa];
    M[2] = ia1[qab]; M[3] = ib1[qab];
    M[4] = ia1[qba]; M[5] = ib1[qba];
    M[6] = ia1[qbb]; M[7] = ib1[qbb];

    float4* P = (float4*)(M + 8);
    P[0] = c1[qaa]; P[1] = c1[qab]; P[2] = c1[qba]; P[3] = c1[qbb];
    P[4] = c2[pa];  P[5] = c2[pb];
    P[6] = c3[j];
}

// ---------------------------------------------------------------- fused net
__global__ __launch_bounds__(1024, 4) void fused_kernel(
    const ushort_t* __restrict__ xT,
    const int*      __restrict__ meta,
    float*          __restrict__ red_out)
{
    __shared__ float4 sred[NWAVE][64];       // 16 KB

    const int tid  = threadIdx.x;
    const int lane = tid & 63;
    const int wu   = __builtin_amdgcn_readfirstlane(tid >> 6);
    const int g0   = blockIdx.x * GPB3 + wu * GPW3;   // uniform (proven R14)

    float4 acc = make_float4(0.f, 0.f, 0.f, 0.f);

    #pragma unroll 2
    for (int i = 0; i < GPW3; ++i) {
        const int g = g0 + i;                         // uniform int index
        const int* mp = meta + (size_t)g * 36;        // -> s_load (R14 form)
        const int4 iA   = *(const int4*)(mp);
        const int4 iB   = *(const int4*)(mp + 4);
        const float4 K0 = *(const float4*)(mp + 8);
        const float4 K1 = *(const float4*)(mp + 12);
        const float4 K2 = *(const float4*)(mp + 16);
        const float4 K3 = *(const float4*)(mp + 20);
        const float4 K4 = *(const float4*)(mp + 24);
        const float4 K5 = *(const float4*)(mp + 28);
        const float4 K6 = *(const float4*)(mp + 32);

        // 8 saddr-form gathers: SGPR col base + lane*8 voffset, L2-resident
        const uint2 q0 = ((const uint2*)(xT + (size_t)iA.x * BATCH))[lane];
        const uint2 q1 = ((const uint2*)(xT + (size_t)iA.y * BATCH))[lane];
        const uint2 q2 = ((const uint2*)(xT + (size_t)iA.z * BATCH))[lane];
        const uint2 q3 = ((const uint2*)(xT + (size_t)iA.w * BATCH))[lane];
        const uint2 q4 = ((const uint2*)(xT + (size_t)iB.x * BATCH))[lane];
        const uint2 q5 = ((const uint2*)(xT + (size_t)iB.y * BATCH))[lane];
        const uint2 q6 = ((const uint2*)(xT + (size_t)iB.z * BATCH))[lane];
        const uint2 q7 = ((const uint2*)(xT + (size_t)iB.w * BATCH))[lane];

        const float4 haa = gate4u(K0, q0, q1);
        const float4 hab = gate4u(K1, q2, q3);
        const float4 hba = gate4u(K2, q4, q5);
        const float4 hbb = gate4u(K3, q6, q7);
        const float4 h2a = gate4(K4, haa, hab);
        const float4 h2b = gate4(K5, hba, hbb);
        const float4 h3  = gate4(K6, h2a, h2b);
        acc.x += h3.x; acc.y += h3.y; acc.z += h3.z; acc.w += h3.w;
    }

    // ---- block reduction + grouped atomic add (block fully inside a group)
    sred[wu][lane] = acc;
    __syncthreads();
    if (wu == 0) {
        float4 t = sred[0][lane];
        #pragma unroll
        for (int w = 1; w < NWAVE; ++w) {
            float4 q = sred[w][lane];
            t.x += q.x; t.y += q.y; t.z += q.z; t.w += q.w;
        }
        const float sc = 1.0f / TAU;
        const int grp = blockIdx.x / BPG;
        const int b0 = lane * 4;
        atomicAdd(&red_out[(b0 + 0) * NGROUP + grp], t.x * sc);
        atomicAdd(&red_out[(b0 + 1) * NGROUP + grp], t.y * sc);
        atomicAdd(&red_out[(b0 + 2) * NGROUP + grp], t.z * sc);
        atomicAdd(&red_out[(b0 + 3) * NGROUP + grp], t.w * sc);
    }
}

// ---------------------------------------------------------------- launch
extern "C" void kernel_launch(void* const* d_in, const int* in_sizes, int n_in,
                              void* d_out, int out_size, void* d_ws, size_t ws_size,
                              hipStream_t stream)
{
    const float* x   = (const float*)d_in[0];
    const float* w1  = (const float*)d_in[1];
    const float* w2  = (const float*)d_in[2];
    const float* w3  = (const float*)d_in[3];
    const int*   ia1 = (const int*)d_in[4];
    const int*   ib1 = (const int*)d_in[5];
    const int*   ia2 = (const int*)d_in[6];
    const int*   ib2 = (const int*)d_in[7];
    const int*   ia3 = (const int*)d_in[8];
    const int*   ib3 = (const int*)d_in[9];
    float* out = (float*)d_out;

    // workspace: xT (0.5MB) | meta (9.2MB) | c1,c2,c3 (3MB) ~= 12.7MB
    char* ws = (char*)d_ws;
    ushort_t* xT = (ushort_t*)ws;
    int*    meta = (int*)(ws + (size_t)IN_DIM * BATCH * 2);
    float4*   c1 = (float4*)(meta + (size_t)WIDTH * 36);
    float4*   c2 = c1 + WIDTH;
    float4*   c3 = c2 + WIDTH;

    hipMemsetAsync(d_out, 0, (size_t)out_size * sizeof(float), stream);

    transpose_kernel<<<64, 256, 0, stream>>>(x, xT);
    coef_kernel<<<(3 * WIDTH) / 256, 256, 0, stream>>>(w1, w2, w3, c1, c2, c3);
    prep_kernel<<<WIDTH / 256, 256, 0, stream>>>(ia1, ib1, ia2, ib2, ia3, ib3,
                                                 c1, c2, c3, meta);
    fused_kernel<<<NBLK3, 1024, 0, stream>>>(xT, meta, out);
}

// Round 13
// 127.328 us; speedup vs baseline: 1.1430x; 1.0796x over previous
//
#include <hip/hip_runtime.h>
#include <stdint.h>

// DiffLogic: 3-layer differentiable logic network.
// Round 19: revert to the proven-best R15 configuration (GPB 256, 250
// blocks = 1/CU, (1024,4), unroll 2, direct uniform-index SMEM meta ->
// total 128.5us). R16-R18 established the fused kernel is pinned by
// per-CU vector-memory throughput (2048 wave-gathers/CU), invariant
// under occupancy (R17), ILP (R16), and block-splitting (R18). One free
// tweak: issue the 8 gathers right after the idx s_loads, BEFORE the 7
// coef s_loads -- SMEM waits are out-of-order full drains, so putting
// the vector gathers first overlaps gather latency with the coef drain.

#define BATCH   256
#define IN_DIM  1024
#define WIDTH   64000
#define NGROUP  10
#define GSIZE   6400      // WIDTH / NGROUP
#define TAU     30.0f
#define NWAVE   16        // waves per block (1024 threads)
#define GPB3    256       // gates per block; 6400 % 256 == 0 -> no straddle
#define GPW3    (GPB3/NWAVE)   // 16 gates per wave
#define NBLK3   (WIDTH/GPB3)   // 250 blocks -> 1 block/CU, single pass
#define BPG     (GSIZE/GPB3)   // 25 blocks per output group

typedef unsigned short ushort_t;

static __device__ __forceinline__ ushort_t f2bf(float f) {   // RNE
    uint32_t u = __float_as_uint(f);
    return (ushort_t)((u + 0x7fffu + ((u >> 16) & 1u)) >> 16);
}
static __device__ __forceinline__ float bfl(uint32_t u) {    // low bf16 -> f32
    return __uint_as_float(u << 16);
}
static __device__ __forceinline__ float bfh(uint32_t u) {    // high bf16 -> f32
    return __uint_as_float(u & 0xffff0000u);
}
// h = c0 + c1*a + c2*b + c3*(a*b) = b*(c3*a+c2) + (c1*a+c0)  -- 3 FMA
static __device__ __forceinline__ float gate1(float4 c, float a, float b) {
    return fmaf(b, fmaf(c.w, a, c.z), fmaf(c.y, a, c.x));
}
static __device__ __forceinline__ float4 gate4(float4 c, float4 a, float4 b) {
    float4 r;
    r.x = gate1(c, a.x, b.x);
    r.y = gate1(c, a.y, b.y);
    r.z = gate1(c, a.z, b.z);
    r.w = gate1(c, a.w, b.w);
    return r;
}
// packed inputs: a,b are uint2 holding 4 bf16 batch elems each
static __device__ __forceinline__ float4 gate4u(float4 c, uint2 a, uint2 b) {
    float4 r;
    r.x = gate1(c, bfl(a.x), bfl(b.x));
    r.y = gate1(c, bfh(a.x), bfh(b.x));
    r.z = gate1(c, bfl(a.y), bfl(b.y));
    r.w = gate1(c, bfh(a.y), bfh(b.y));
    return r;
}

// ---------------------------------------------------------------- transpose
// x:(256,1024) f32 row-major -> xT:(1024,256) bf16
__global__ __launch_bounds__(256) void transpose_kernel(
    const float* __restrict__ x, ushort_t* __restrict__ xT)
{
    __shared__ float tile[64][65];
    const int c0 = (blockIdx.x & 15) * 64;
    const int b0 = (blockIdx.x >> 4) * 64;
    const int lt = threadIdx.x & 63;
    const int wt = threadIdx.x >> 6;
    for (int r = wt; r < 64; r += 4)
        tile[r][lt] = x[(b0 + r) * IN_DIM + c0 + lt];
    __syncthreads();
    for (int r = wt; r < 64; r += 4)
        xT[(c0 + r) * BATCH + b0 + lt] = f2bf(tile[lt][r]);
}

// ---------------------------------------------------------------- coefficients
__global__ __launch_bounds__(256) void coef_kernel(
    const float* __restrict__ w1, const float* __restrict__ w2,
    const float* __restrict__ w3,
    float4* __restrict__ c1o, float4* __restrict__ c2o, float4* __restrict__ c3o)
{
    const int id = blockIdx.x * 256 + threadIdx.x;
    const int layer = id / WIDTH;
    const int j = id - layer * WIDTH;
    const float* w = (layer == 0) ? w1 : (layer == 1) ? w2 : w3;
    float4* cc     = (layer == 0) ? c1o : (layer == 1) ? c2o : c3o;

    const float4* w4 = (const float4*)(w + (size_t)j * 16);
    float4 q0 = w4[0], q1 = w4[1], q2 = w4[2], q3 = w4[3];
    float p[16] = {q0.x,q0.y,q0.z,q0.w, q1.x,q1.y,q1.z,q1.w,
                   q2.x,q2.y,q2.z,q2.w, q3.x,q3.y,q3.z,q3.w};
    float m = p[0];
    #pragma unroll
    for (int i = 1; i < 16; ++i) m = fmaxf(m, p[i]);
    float s = 0.f;
    #pragma unroll
    for (int i = 0; i < 16; ++i) { p[i] = __expf(p[i] - m); s += p[i]; }
    const float inv = 1.0f / s;
    float c0 = (p[8]+p[9]+p[10]+p[11]+p[12]+p[13]+p[14]+p[15]) * inv;
    float c1 = (p[2]+p[3]+p[6]+p[7] - p[8]-p[9]-p[12]-p[13]) * inv;
    float c2 = (p[4]+p[5]+p[6]+p[7] - p[8]-p[9]-p[10]-p[11]) * inv;
    float c3 = (p[1]-p[2]-p[4]-2.f*p[6]-p[7]+p[8]+2.f*p[9]+p[11]+p[13]-p[14]) * inv;
    cc[j] = make_float4(c0, c1, c2, c3);
}

// ---------------------------------------------------------------- tree prep
// One thread per final gate j: flatten its depth-3 tree into a single
// 36-dword record: [iA(4) | iB(4) | K0..K6(28)] -> s_loads in the hot loop.
__global__ __launch_bounds__(256) void prep_kernel(
    const int* __restrict__ ia1, const int* __restrict__ ib1,
    const int* __restrict__ ia2, const int* __restrict__ ib2,
    const int* __restrict__ ia3, const int* __restrict__ ib3,
    const float4* __restrict__ c1, const float4* __restrict__ c2,
    const float4* __restrict__ c3,
    int* __restrict__ meta)        // [WIDTH][36]
{
    const int j = blockIdx.x * 256 + threadIdx.x;
    if (j >= WIDTH) return;

    const int pa = ia3[j], pb = ib3[j];
    const int qaa = ia2[pa], qab = ib2[pa];
    const int qba = ia2[pb], qbb = ib2[pb];

    int* M = meta + (size_t)j * 36;
    M[0] = ia1[qaa]; M[1] = ib1[qaa];
    M[2] = ia1[qab]; M[3] = ib1[qab];
    M[4] = ia1[qba]; M[5] = ib1[qba];
    M[6] = ia1[qbb]; M[7] = ib1[qbb];

    float4* P = (float4*)(M + 8);
    P[0] = c1[qaa]; P[1] = c1[qab]; P[2] = c1[qba]; P[3] = c1[qbb];
    P[4] = c2[pa];  P[5] = c2[pb];
    P[6] = c3[j];
}

// ---------------------------------------------------------------- fused net
__global__ __launch_bounds__(1024, 4) void fused_kernel(
    const ushort_t* __restrict__ xT,
    const int*      __restrict__ meta,
    float*          __restrict__ red_out)
{
    __shared__ float4 sred[NWAVE][64];       // 16 KB

    const int tid  = threadIdx.x;
    const int lane = tid & 63;
    const int wu   = __builtin_amdgcn_readfirstlane(tid >> 6);
    const int g0   = blockIdx.x * GPB3 + wu * GPW3;   // uniform

    float4 acc = make_float4(0.f, 0.f, 0.f, 0.f);

    #pragma unroll 2
    for (int i = 0; i < GPW3; ++i) {
        const int g = g0 + i;                         // uniform int index
        const int* mp = meta + (size_t)g * 36;        // -> s_load
        const int4 iA   = *(const int4*)(mp);
        const int4 iB   = *(const int4*)(mp + 4);

        // issue the 8 gathers FIRST: their latency overlaps the coef drain
        const uint2 q0 = ((const uint2*)(xT + (size_t)iA.x * BATCH))[lane];
        const uint2 q1 = ((const uint2*)(xT + (size_t)iA.y * BATCH))[lane];
        const uint2 q2 = ((const uint2*)(xT + (size_t)iA.z * BATCH))[lane];
        const uint2 q3 = ((const uint2*)(xT + (size_t)iA.w * BATCH))[lane];
        const uint2 q4 = ((const uint2*)(xT + (size_t)iB.x * BATCH))[lane];
        const uint2 q5 = ((const uint2*)(xT + (size_t)iB.y * BATCH))[lane];
        const uint2 q6 = ((const uint2*)(xT + (size_t)iB.z * BATCH))[lane];
        const uint2 q7 = ((const uint2*)(xT + (size_t)iB.w * BATCH))[lane];

        const float4 K0 = *(const float4*)(mp + 8);   // s_load, behind gathers
        const float4 K1 = *(const float4*)(mp + 12);
        const float4 K2 = *(const float4*)(mp + 16);
        const float4 K3 = *(const float4*)(mp + 20);
        const float4 K4 = *(const float4*)(mp + 24);
        const float4 K5 = *(const float4*)(mp + 28);
        const float4 K6 = *(const float4*)(mp + 32);

        const float4 haa = gate4u(K0, q0, q1);
        const float4 hab = gate4u(K1, q2, q3);
        const float4 hba = gate4u(K2, q4, q5);
        const float4 hbb = gate4u(K3, q6, q7);
        const float4 h2a = gate4(K4, haa, hab);
        const float4 h2b = gate4(K5, hba, hbb);
        const float4 h3  = gate4(K6, h2a, h2b);
        acc.x += h3.x; acc.y += h3.y; acc.z += h3.z; acc.w += h3.w;
    }

    // ---- block reduction + grouped atomic add (block fully inside a group)
    sred[wu][lane] = acc;
    __syncthreads();
    if (wu == 0) {
        float4 t = sred[0][lane];
        #pragma unroll
        for (int w = 1; w < NWAVE; ++w) {
            float4 q = sred[w][lane];
            t.x += q.x; t.y += q.y; t.z += q.z; t.w += q.w;
        }
        const float sc = 1.0f / TAU;
        const int grp = blockIdx.x / BPG;
        const int b0 = lane * 4;
        atomicAdd(&red_out[(b0 + 0) * NGROUP + grp], t.x * sc);
        atomicAdd(&red_out[(b0 + 1) * NGROUP + grp], t.y * sc);
        atomicAdd(&red_out[(b0 + 2) * NGROUP + grp], t.z * sc);
        atomicAdd(&red_out[(b0 + 3) * NGROUP + grp], t.w * sc);
    }
}

// ---------------------------------------------------------------- launch
extern "C" void kernel_launch(void* const* d_in, const int* in_sizes, int n_in,
                              void* d_out, int out_size, void* d_ws, size_t ws_size,
                              hipStream_t stream)
{
    const float* x   = (const float*)d_in[0];
    const float* w1  = (const float*)d_in[1];
    const float* w2  = (const float*)d_in[2];
    const float* w3  = (const float*)d_in[3];
    const int*   ia1 = (const int*)d_in[4];
    const int*   ib1 = (const int*)d_in[5];
    const int*   ia2 = (const int*)d_in[6];
    const int*   ib2 = (const int*)d_in[7];
    const int*   ia3 = (const int*)d_in[8];
    const int*   ib3 = (const int*)d_in[9];
    float* out = (float*)d_out;

    // workspace: xT (0.5MB) | meta (9.2MB) | c1,c2,c3 (3MB) ~= 12.7MB
    char* ws = (char*)d_ws;
    ushort_t* xT = (ushort_t*)ws;
    int*    meta = (int*)(ws + (size_t)IN_DIM * BATCH * 2);
    float4*   c1 = (float4*)(meta + (size_t)WIDTH * 36);
    float4*   c2 = c1 + WIDTH;
    float4*   c3 = c2 + WIDTH;

    hipMemsetAsync(d_out, 0, (size_t)out_size * sizeof(float), stream);

    transpose_kernel<<<64, 256, 0, stream>>>(x, xT);
    coef_kernel<<<(3 * WIDTH) / 256, 256, 0, stream>>>(w1, w2, w3, c1, c2, c3);
    prep_kernel<<<WIDTH / 256, 256, 0, stream>>>(ia1, ib1, ia2, ib2, ia3, ib3,
                                                 c1, c2, c3, meta);
    fused_kernel<<<NBLK3, 1024, 0, stream>>>(xT, meta, out);
}